// Round 14
// baseline (58.457 us; speedup 1.0000x reference)
//
#include <hip/hip_runtime.h>
#include <math.h>

#define NB   8
#define NK   64
#define NL   1024
#define NCP  32
#define NAP  8
#define NG2  9
#define NCSA 16
#define NASA 16
#define NG3  3
#define NOC  256      // = NCP*NAP = NCSA*NASA
#define EPSQ 1e-8f
#define VROW 129      // Vb row stride in DWORDS (258 bf16 = 129 dwords)

typedef __bf16 bfv8 __attribute__((ext_vector_type(8)));
typedef float  f32x4 __attribute__((ext_vector_type(4)));

static __device__ inline unsigned short bfbits(float v) {
    __bf16 h = (__bf16)v;
    return __builtin_bit_cast(unsigned short, h);
}
static __device__ inline unsigned int bfpack2(float v0, float v1) {
    return (unsigned int)bfbits(v0) | ((unsigned int)bfbits(v1) << 16);
}
static __device__ inline float frcp(float x) { return __builtin_amdgcn_rcpf(x); }
static __device__ inline float frsq(float x) { return __builtin_amdgcn_rsqf(x); }

// ---------------- k0: prep — transpose operands to bf16 hi planes ------------
__global__ __launch_bounds__(256) void k0_prep(
    const float* __restrict__ x, const float* __restrict__ w1,
    const float* __restrict__ w2,
    __bf16* __restrict__ xThi, __bf16* __restrict__ w1Thi,
    __bf16* __restrict__ w2hi)
{
    const int tid = threadIdx.x;
    const int bid = blockIdx.x;
    if (bid < 128) {
        __shared__ float tile[64][65];
        const int b = bid >> 4, l0 = (bid & 15) * 64;
        const float* xb = x + (size_t)b * NK * NL;
        const int lcol = tid & 63, kr = tid >> 6;
#pragma unroll
        for (int pass = 0; pass < 16; ++pass) {
            int kk = pass * 4 + kr;
            tile[lcol][kk] = xb[(size_t)kk * NL + l0 + lcol];
        }
        __syncthreads();
        const int lr = tid >> 5, pc = tid & 31;
#pragma unroll
        for (int pass = 0; pass < 8; ++pass) {
            int ll = pass * 8 + lr;
            float v0 = tile[ll][pc * 2], v1 = tile[ll][pc * 2 + 1];
            size_t base = ((size_t)b * NL + l0 + ll) * 64 + pc * 2;
            *(unsigned int*)(xThi + base) = bfpack2(v0, v1);
        }
    } else if (bid < 128 + 288) {
        int idx = (bid - 128) * 256 + tid;
        int kp = idx & 31, rest = idx >> 5;
        int oc = rest & 255, g = rest >> 8;
        float v0 = w1[(size_t)oc * 576 + (kp * 2) * NG2 + g];
        float v1 = w1[(size_t)oc * 576 + (kp * 2 + 1) * NG2 + g];
        size_t base = ((size_t)(g * NOC + oc)) * 64 + kp * 2;
        *(unsigned int*)(w1Thi + base) = bfpack2(v0, v1);
    } else {
        for (int i = tid; i < NOC * 24; i += 256) {
            w2hi[i] = (__bf16)w2[i];
        }
    }
}

// ---------------- k1: conv1 via MFMA (9 shifted K=64 GEMMs) + squash ---------
// R13 version (hi-only, proven).
__global__ __launch_bounds__(256) void k1_mfma(
    const __bf16* __restrict__ xThi, const __bf16* __restrict__ w1Thi,
    const float* __restrict__ b1, __bf16* __restrict__ ysq)
{
    __shared__ alignas(16) __bf16 xph[72][64];
    const int tid = threadIdx.x;
    const int bid = blockIdx.x;
    const int ocb = bid & 3;
    const int lb  = (bid >> 2) & 15;
    const int b   = bid >> 6;
    const int l0  = lb * 64;

    {
        const int row0 = tid >> 3, seg = tid & 7;
#pragma unroll
        for (int p = 0; p < 3; ++p) {
            int row = p * 32 + row0;
            if (row < 72) {
                int l = l0 - 4 + row;
                int sw = seg ^ (row & 7);
                uint4 vh = {0u,0u,0u,0u};
                if (l >= 0 && l < NL) {
                    size_t off = ((size_t)b * NL + l) * 64 + seg * 8;
                    vh = *(const uint4*)(xThi + off);
                }
                *(uint4*)(&xph[row][sw * 8]) = vh;
            }
        }
    }
    __syncthreads();

    const int lane = tid & 63, wv = tid >> 6;
    const int qq = lane >> 4, cr = lane & 15;
    const int oco = ocb * 64 + wv * 16;

    f32x4 acc[4];
#pragma unroll
    for (int lt = 0; lt < 4; ++lt) acc[lt] = (f32x4){0.f, 0.f, 0.f, 0.f};

    for (int g = 0; g < NG2; ++g) {
#pragma unroll
        for (int s = 0; s < 2; ++s) {
            size_t aoff = ((size_t)(g * NOC + oco + cr)) * 64 + s * 32 + qq * 8;
            bfv8 Ahi = *(const bfv8*)(w1Thi + aoff);
#pragma unroll
            for (int lt = 0; lt < 4; ++lt) {
                int row = lt * 16 + cr + g;
                int gr = (s * 4 + qq) ^ (row & 7);
                bfv8 Bhi = *(const bfv8*)(&xph[row][gr * 8]);
                acc[lt] = __builtin_amdgcn_mfma_f32_16x16x32_bf16(Ahi, Bhi, acc[lt], 0, 0, 0);
            }
        }
    }

    const float4 bv = *(const float4*)(b1 + oco + qq * 4);
#pragma unroll
    for (int lt = 0; lt < 4; ++lt) {
        float v0 = acc[lt][0] + bv.x, v1 = acc[lt][1] + bv.y;
        float v2 = acc[lt][2] + bv.z, v3 = acc[lt][3] + bv.w;
        float s = v0*v0 + v1*v1 + v2*v2 + v3*v3;
        float s8 = s + __shfl_xor(s, 16);
        float scale = s8 * frcp(1.0f + s8) * frsq(s8 + EPSQ);
        uint2 st;
        st.x = bfpack2(v0 * scale, v1 * scale);
        st.y = bfpack2(v2 * scale, v3 * scale);
        int l = l0 + lt * 16 + cr;
        *(uint2*)(ysq + ((size_t)b * NL + l) * NOC + oco + qq * 4) = st;
    }
}

// ---------------- k2: conv2 + routing, TWO sites (l, l+1) per block ----------
// ILP-interleave: every serial chain (shuffle tree, exp, squash) has an
// independent twin; barriers 5 per 2 sites; w2/b2 fragments shared by both
// sites. Explicit A/B register naming (no runtime-indexed arrays -> no
// scratch). launch_bounds(256,2): VGPR cap 256 >> ~110 need (no strangle);
// LDS 40.2 KB -> 4 blocks/CU. a-step rows read from LDS (ar-hoist dropped
// to fund VregB's 32 regs).
__global__ __launch_bounds__(256, 2) void k2_conv2_routing(
    const __bf16* __restrict__ ysq,
    const __bf16* __restrict__ w2hi,
    const float* __restrict__ b2, float* __restrict__ out)
{
    __shared__ alignas(16) unsigned int VbWA[NCP * VROW];  // 16512 B
    __shared__ alignas(16) unsigned int VbWB[NCP * VROW];  // 16512 B
    __shared__ alignas(16) float cctA[NCSA][36];           //  2304 B
    __shared__ alignas(16) float cctB[NCSA][36];           //  2304 B
    __shared__ alignas(16) float vvsA[NCSA][20];           //  1280 B
    __shared__ alignas(16) float vvsB[NCSA][20];           //  1280 B -> 40192 B

    const int tid = threadIdx.x;
    const int bid = blockIdx.x;
    const int b  = bid >> 9;
    const int lA = (bid & 511) * 2;
    const int lB = lA + 1;

    const int lane = tid & 63;
    const int wv   = tid >> 6;
    const int q    = lane >> 4;
    const int cr   = lane & 15;

    const __bf16* ybaseA = ysq + ((size_t)b * NL + lA) * NOC;
    const __bf16* ybaseB = ybaseA + NOC;
    const bool okA = (q == 1) || (q == 0 && lA > 0) || (q == 2);            // lA+1 <= 1022 < NL-1? lA max 1022 -> lA+1 ok
    const bool okB = (q == 1) || (q == 0) || (q == 2 && lB < NL - 1);       // lB-1 = lA >= 0 always
    bfv8 B0A, B1A, B0B, B1B;
    if (okA) {
        B0A = *(const bfv8*)(ybaseA + (q - 1) * NOC + cr * 8);
        B1A = *(const bfv8*)(ybaseA + (q - 1) * NOC + (cr + 16) * 8);
    } else {
#pragma unroll
        for (int i = 0; i < 8; ++i) { B0A[i] = (__bf16)0.0f; B1A[i] = (__bf16)0.0f; }
    }
    if (okB) {
        B0B = *(const bfv8*)(ybaseB + (q - 1) * NOC + cr * 8);
        B1B = *(const bfv8*)(ybaseB + (q - 1) * NOC + (cr + 16) * 8);
    } else {
#pragma unroll
        for (int i = 0; i < 8; ++i) { B0B[i] = (__bf16)0.0f; B1B[i] = (__bf16)0.0f; }
    }

    const int swz0 = (cr & 3) << 3;
#pragma unroll
    for (int i = 0; i < 4; ++i) {
        const int t  = wv * 4 + i;
        const int oc = t * 16 + cr;
        bfv8 Ahi;
        if (q < 3) {
            Ahi = *(const bfv8*)(w2hi + oc * 24 + q * 8);
        } else {
#pragma unroll
            for (int j = 0; j < 8; ++j) Ahi[j] = (__bf16)0.0f;
        }

        f32x4 aA0 = {0.f,0.f,0.f,0.f}, aA1 = {0.f,0.f,0.f,0.f};
        f32x4 aB0 = {0.f,0.f,0.f,0.f}, aB1 = {0.f,0.f,0.f,0.f};
        aA0 = __builtin_amdgcn_mfma_f32_16x16x32_bf16(Ahi, B0A, aA0, 0, 0, 0);
        aA1 = __builtin_amdgcn_mfma_f32_16x16x32_bf16(Ahi, B1A, aA1, 0, 0, 0);
        aB0 = __builtin_amdgcn_mfma_f32_16x16x32_bf16(Ahi, B0B, aB0, 0, 0, 0);
        aB1 = __builtin_amdgcn_mfma_f32_16x16x32_bf16(Ahi, B1B, aB1, 0, 0, 0);

        const int r0 = t * 16 + q * 4;
        float4 bvv = *(const float4*)(b2 + r0);
        const int D  = t * 8 + q * 2;
        const int d0 = D ^ swz0;
        VbWA[cr * VROW + d0]            = bfpack2(aA0[0] + bvv.x, aA0[1] + bvv.y);
        VbWA[cr * VROW + d0 + 1]        = bfpack2(aA0[2] + bvv.z, aA0[3] + bvv.w);
        VbWA[(cr + 16) * VROW + d0]     = bfpack2(aA1[0] + bvv.x, aA1[1] + bvv.y);
        VbWA[(cr + 16) * VROW + d0 + 1] = bfpack2(aA1[2] + bvv.z, aA1[3] + bvv.w);
        VbWB[cr * VROW + d0]            = bfpack2(aB0[0] + bvv.x, aB0[1] + bvv.y);
        VbWB[cr * VROW + d0 + 1]        = bfpack2(aB0[2] + bvv.z, aB0[3] + bvv.w);
        VbWB[(cr + 16) * VROW + d0]     = bfpack2(aB1[0] + bvv.x, aB1[1] + bvv.y);
        VbWB[(cr + 16) * VROW + d0 + 1] = bfpack2(aB1[2] + bvv.z, aB1[3] + bvv.w);
    }
    __syncthreads();   // (1) V visible

    // ---- routing ----
    const int csa = tid >> 4, asa = tid & 15;
    const int cp8 = tid >> 3, cs = tid & 7;

    float VregA[NCP], VregB[NCP];
    {
        const __bf16* vbA = (const __bf16*)VbWA;
        const __bf16* vbB = (const __bf16*)VbWB;
        const int tw = tid >> 1, th = tid & 1;
#pragma unroll
        for (int cp = 0; cp < NCP; ++cp) {
            int d = tw ^ ((cp & 3) << 3);
            VregA[cp] = (float)vbA[cp * (2 * VROW) + d * 2 + th];
            VregB[cp] = (float)vbB[cp * (2 * VROW) + d * 2 + th];
        }
    }

    const int aoff0 = cp8 * VROW + ((cs * 8) ^ ((cp8 & 3) << 3));
    const int aoff1 = cp8 * VROW + (((cs + 8) * 8) ^ ((cp8 & 3) << 3));

    float brA0, brA1, brB0, brB1;

    // ---- r = 0: logits 0 -> uniform softmax (1/16)
    {
        float sA0=0.f,sA1=0.f,sA2=0.f,sA3=0.f, sB0=0.f,sB1=0.f,sB2=0.f,sB3=0.f;
#pragma unroll
        for (int cp = 0; cp < NCP; cp += 4) {
            sA0 += VregA[cp];     sA1 += VregA[cp + 1];
            sA2 += VregA[cp + 2]; sA3 += VregA[cp + 3];
            sB0 += VregB[cp];     sB1 += VregB[cp + 1];
            sB2 += VregB[cp + 2]; sB3 += VregB[cp + 3];
        }
        float svA = ((sA0 + sA1) + (sA2 + sA3)) * 0.0625f;
        float svB = ((sB0 + sB1) + (sB2 + sB3)) * 0.0625f;
        float sqA = svA * svA, sqB = svB * svB;
        sqA += __shfl_xor(sqA, 1);  sqB += __shfl_xor(sqB, 1);
        sqA += __shfl_xor(sqA, 2);  sqB += __shfl_xor(sqB, 2);
        sqA += __shfl_xor(sqA, 4);  sqB += __shfl_xor(sqB, 4);
        sqA += __shfl_xor(sqA, 8);  sqB += __shfl_xor(sqB, 8);
        vvsA[csa][asa] = svA * sqA * frcp(1.0f + sqA) * frsq(sqA + EPSQ);
        vvsB[csa][asa] = svB * sqB * frcp(1.0f + sqB) * frsq(sqB + EPSQ);
        __syncthreads();   // (2) vv r0

        float aA0a=0.f,aA0b=0.f,aA1a=0.f,aA1b=0.f;
        float aB0a=0.f,aB0b=0.f,aB1a=0.f,aB1b=0.f;
#pragma unroll
        for (int j = 0; j < 8; ++j) {
            unsigned int dA0 = VbWA[aoff0 + j], dA1 = VbWA[aoff1 + j];
            unsigned int dB0 = VbWB[aoff0 + j], dB1 = VbWB[aoff1 + j];
            float2 vA0 = *(const float2*)(&vvsA[cs][2 * j]);
            float2 vA1 = *(const float2*)(&vvsA[cs + 8][2 * j]);
            float2 vB0 = *(const float2*)(&vvsB[cs][2 * j]);
            float2 vB1 = *(const float2*)(&vvsB[cs + 8][2 * j]);
            aA0a = fmaf(__builtin_bit_cast(float, dA0 << 16),         vA0.x, aA0a);
            aA0b = fmaf(__builtin_bit_cast(float, dA0 & 0xFFFF0000u), vA0.y, aA0b);
            aA1a = fmaf(__builtin_bit_cast(float, dA1 << 16),         vA1.x, aA1a);
            aA1b = fmaf(__builtin_bit_cast(float, dA1 & 0xFFFF0000u), vA1.y, aA1b);
            aB0a = fmaf(__builtin_bit_cast(float, dB0 << 16),         vB0.x, aB0a);
            aB0b = fmaf(__builtin_bit_cast(float, dB0 & 0xFFFF0000u), vB0.y, aB0b);
            aB1a = fmaf(__builtin_bit_cast(float, dB1 << 16),         vB1.x, aB1a);
            aB1b = fmaf(__builtin_bit_cast(float, dB1 & 0xFFFF0000u), vB1.y, aB1b);
        }
        brA0 = aA0a + aA0b;  brA1 = aA1a + aA1b;
        brB0 = aB0a + aB0b;  brB1 = aB1a + aB1b;
    }

    // ---- r = 1
    {
        float eA0 = __expf(brA0), eA1 = __expf(brA1);
        float eB0 = __expf(brB0), eB1 = __expf(brB1);
        float smA = eA0 + eA1, smB = eB0 + eB1;
        smA += __shfl_xor(smA, 1);  smB += __shfl_xor(smB, 1);
        smA += __shfl_xor(smA, 2);  smB += __shfl_xor(smB, 2);
        smA += __shfl_xor(smA, 4);  smB += __shfl_xor(smB, 4);
        float invA = frcp(smA), invB = frcp(smB);
        cctA[cs][cp8]     = eA0 * invA;
        cctA[cs + 8][cp8] = eA1 * invA;
        cctB[cs][cp8]     = eB0 * invB;
        cctB[cs + 8][cp8] = eB1 * invB;
        __syncthreads();   // (3) cc r1

        float sA0=0.f,sA1=0.f,sA2=0.f,sA3=0.f, sB0=0.f,sB1=0.f,sB2=0.f,sB3=0.f;
        const float4* crA = (const float4*)(&cctA[csa][0]);
        const float4* crB = (const float4*)(&cctB[csa][0]);
#pragma unroll
        for (int jj = 0; jj < 8; ++jj) {
            float4 cA = crA[jj], cB = crB[jj];
            sA0 = fmaf(cA.x, VregA[4*jj+0], sA0);  sA1 = fmaf(cA.y, VregA[4*jj+1], sA1);
            sA2 = fmaf(cA.z, VregA[4*jj+2], sA2);  sA3 = fmaf(cA.w, VregA[4*jj+3], sA3);
            sB0 = fmaf(cB.x, VregB[4*jj+0], sB0);  sB1 = fmaf(cB.y, VregB[4*jj+1], sB1);
            sB2 = fmaf(cB.z, VregB[4*jj+2], sB2);  sB3 = fmaf(cB.w, VregB[4*jj+3], sB3);
        }
        float svA = (sA0 + sA1) + (sA2 + sA3);
        float svB = (sB0 + sB1) + (sB2 + sB3);
        float sqA = svA * svA, sqB = svB * svB;
        sqA += __shfl_xor(sqA, 1);  sqB += __shfl_xor(sqB, 1);
        sqA += __shfl_xor(sqA, 2);  sqB += __shfl_xor(sqB, 2);
        sqA += __shfl_xor(sqA, 4);  sqB += __shfl_xor(sqB, 4);
        sqA += __shfl_xor(sqA, 8);  sqB += __shfl_xor(sqB, 8);
        vvsA[csa][asa] = svA * sqA * frcp(1.0f + sqA) * frsq(sqA + EPSQ);
        vvsB[csa][asa] = svB * sqB * frcp(1.0f + sqB) * frsq(sqB + EPSQ);
        __syncthreads();   // (4) vv r1

        float aA0a=0.f,aA0b=0.f,aA1a=0.f,aA1b=0.f;
        float aB0a=0.f,aB0b=0.f,aB1a=0.f,aB1b=0.f;
#pragma unroll
        for (int j = 0; j < 8; ++j) {
            unsigned int dA0 = VbWA[aoff0 + j], dA1 = VbWA[aoff1 + j];
            unsigned int dB0 = VbWB[aoff0 + j], dB1 = VbWB[aoff1 + j];
            float2 vA0 = *(const float2*)(&vvsA[cs][2 * j]);
            float2 vA1 = *(const float2*)(&vvsA[cs + 8][2 * j]);
            float2 vB0 = *(const float2*)(&vvsB[cs][2 * j]);
            float2 vB1 = *(const float2*)(&vvsB[cs + 8][2 * j]);
            aA0a = fmaf(__builtin_bit_cast(float, dA0 << 16),         vA0.x, aA0a);
            aA0b = fmaf(__builtin_bit_cast(float, dA0 & 0xFFFF0000u), vA0.y, aA0b);
            aA1a = fmaf(__builtin_bit_cast(float, dA1 << 16),         vA1.x, aA1a);
            aA1b = fmaf(__builtin_bit_cast(float, dA1 & 0xFFFF0000u), vA1.y, aA1b);
            aB0a = fmaf(__builtin_bit_cast(float, dB0 << 16),         vB0.x, aB0a);
            aB0b = fmaf(__builtin_bit_cast(float, dB0 & 0xFFFF0000u), vB0.y, aB0b);
            aB1a = fmaf(__builtin_bit_cast(float, dB1 << 16),         vB1.x, aB1a);
            aB1b = fmaf(__builtin_bit_cast(float, dB1 & 0xFFFF0000u), vB1.y, aB1b);
        }
        brA0 += aA0a + aA0b;  brA1 += aA1a + aA1b;
        brB0 += aB0a + aB0b;  brB1 += aB1a + aB1b;
    }

    // ---- r = 2 (final)
    {
        float eA0 = __expf(brA0), eA1 = __expf(brA1);
        float eB0 = __expf(brB0), eB1 = __expf(brB1);
        float smA = eA0 + eA1, smB = eB0 + eB1;
        smA += __shfl_xor(smA, 1);  smB += __shfl_xor(smB, 1);
        smA += __shfl_xor(smA, 2);  smB += __shfl_xor(smB, 2);
        smA += __shfl_xor(smA, 4);  smB += __shfl_xor(smB, 4);
        float invA = frcp(smA), invB = frcp(smB);
        cctA[cs][cp8]     = eA0 * invA;
        cctA[cs + 8][cp8] = eA1 * invA;
        cctB[cs][cp8]     = eB0 * invB;
        cctB[cs + 8][cp8] = eB1 * invB;
        __syncthreads();   // (5) cc r2

        float sA0=0.f,sA1=0.f,sA2=0.f,sA3=0.f, sB0=0.f,sB1=0.f,sB2=0.f,sB3=0.f;
        const float4* crA = (const float4*)(&cctA[csa][0]);
        const float4* crB = (const float4*)(&cctB[csa][0]);
#pragma unroll
        for (int jj = 0; jj < 8; ++jj) {
            float4 cA = crA[jj], cB = crB[jj];
            sA0 = fmaf(cA.x, VregA[4*jj+0], sA0);  sA1 = fmaf(cA.y, VregA[4*jj+1], sA1);
            sA2 = fmaf(cA.z, VregA[4*jj+2], sA2);  sA3 = fmaf(cA.w, VregA[4*jj+3], sA3);
            sB0 = fmaf(cB.x, VregB[4*jj+0], sB0);  sB1 = fmaf(cB.y, VregB[4*jj+1], sB1);
            sB2 = fmaf(cB.z, VregB[4*jj+2], sB2);  sB3 = fmaf(cB.w, VregB[4*jj+3], sB3);
        }
        float svA = (sA0 + sA1) + (sA2 + sA3);
        float svB = (sB0 + sB1) + (sB2 + sB3);
        float sqA = svA * svA, sqB = svB * svB;
        sqA += __shfl_xor(sqA, 1);  sqB += __shfl_xor(sqB, 1);
        sqA += __shfl_xor(sqA, 2);  sqB += __shfl_xor(sqB, 2);
        sqA += __shfl_xor(sqA, 4);  sqB += __shfl_xor(sqB, 4);
        sqA += __shfl_xor(sqA, 8);  sqB += __shfl_xor(sqB, 8);
        float vA = svA * sqA * frcp(1.0f + sqA) * frsq(sqA + EPSQ);
        float vB = svB * sqB * frcp(1.0f + sqB) * frsq(sqB + EPSQ);
        float* outA = out + ((size_t)b * NL + lA) * NOC + tid;
        outA[0]   = vA;
        outA[NOC] = vB;
    }
}

extern "C" void kernel_launch(void* const* d_in, const int* in_sizes, int n_in,
                              void* d_out, int out_size, void* d_ws, size_t ws_size,
                              hipStream_t stream)
{
    const float* x  = (const float*)d_in[0];
    const float* w1 = (const float*)d_in[1];
    const float* b1 = (const float*)d_in[2];
    const float* w2 = (const float*)d_in[3];
    const float* b2 = (const float*)d_in[4];
    float* outp = (float*)d_out;

    char* ws = (char*)d_ws;
    __bf16* ysq   = (__bf16*)(ws);                 // 4,194,304
    __bf16* xThi  = (__bf16*)(ws + 4194304);       // 1,048,576
    __bf16* w1Thi = (__bf16*)(ws + 5242880);       //   294,912
    __bf16* w2hi  = (__bf16*)(ws + 5537792);       //    12,288

    k0_prep<<<417, 256, 0, stream>>>(x, w1, w2, xThi, w1Thi, w2hi);
    k1_mfma<<<512, 256, 0, stream>>>(xThi, w1Thi, b1, ysq);
    k2_conv2_routing<<<NB * NL / 2, 256, 0, stream>>>(ysq, w2hi, b2, outp);
}

// Round 15
// 54.970 us; speedup vs baseline: 1.0634x; 1.0634x over previous
//
#include <hip/hip_runtime.h>
#include <math.h>

#define NB   8
#define NK   64
#define NL   1024
#define NCP  32
#define NAP  8
#define NG2  9
#define NCSA 16
#define NASA 16
#define NG3  3
#define NOC  256      // = NCP*NAP = NCSA*NASA
#define EPSQ 1e-8f
#define VROW 129      // Vb row stride in DWORDS (258 bf16 = 129 dwords)

typedef __bf16 bfv8 __attribute__((ext_vector_type(8)));
typedef float  f32x4 __attribute__((ext_vector_type(4)));

static __device__ inline unsigned short bfbits(float v) {
    __bf16 h = (__bf16)v;
    return __builtin_bit_cast(unsigned short, h);
}
static __device__ inline unsigned int bfpack2(float v0, float v1) {
    return (unsigned int)bfbits(v0) | ((unsigned int)bfbits(v1) << 16);
}
static __device__ inline float frcp(float x) { return __builtin_amdgcn_rcpf(x); }
static __device__ inline float frsq(float x) { return __builtin_amdgcn_rsqf(x); }

// ---------------- k0: prep — transpose operands to bf16 hi planes ------------
// (R13 proven: all operands hi-only; lo-term drops verified harmless R11-R13)
__global__ __launch_bounds__(256) void k0_prep(
    const float* __restrict__ x, const float* __restrict__ w1,
    const float* __restrict__ w2,
    __bf16* __restrict__ xThi, __bf16* __restrict__ w1Thi,
    __bf16* __restrict__ w2hi)
{
    const int tid = threadIdx.x;
    const int bid = blockIdx.x;
    if (bid < 128) {
        __shared__ float tile[64][65];
        const int b = bid >> 4, l0 = (bid & 15) * 64;
        const float* xb = x + (size_t)b * NK * NL;
        const int lcol = tid & 63, kr = tid >> 6;
#pragma unroll
        for (int pass = 0; pass < 16; ++pass) {
            int kk = pass * 4 + kr;
            tile[lcol][kk] = xb[(size_t)kk * NL + l0 + lcol];
        }
        __syncthreads();
        const int lr = tid >> 5, pc = tid & 31;
#pragma unroll
        for (int pass = 0; pass < 8; ++pass) {
            int ll = pass * 8 + lr;
            float v0 = tile[ll][pc * 2], v1 = tile[ll][pc * 2 + 1];
            size_t base = ((size_t)b * NL + l0 + ll) * 64 + pc * 2;
            *(unsigned int*)(xThi + base) = bfpack2(v0, v1);
        }
    } else if (bid < 128 + 288) {
        int idx = (bid - 128) * 256 + tid;
        int kp = idx & 31, rest = idx >> 5;
        int oc = rest & 255, g = rest >> 8;
        float v0 = w1[(size_t)oc * 576 + (kp * 2) * NG2 + g];
        float v1 = w1[(size_t)oc * 576 + (kp * 2 + 1) * NG2 + g];
        size_t base = ((size_t)(g * NOC + oc)) * 64 + kp * 2;
        *(unsigned int*)(w1Thi + base) = bfpack2(v0, v1);
    } else {
        for (int i = tid; i < NOC * 24; i += 256) {
            w2hi[i] = (__bf16)w2[i];
        }
    }
}

// ---------------- k1: conv1 via MFMA (9 shifted K=64 GEMMs) + squash ---------
// R13 version (hi-only, proven best).
__global__ __launch_bounds__(256) void k1_mfma(
    const __bf16* __restrict__ xThi, const __bf16* __restrict__ w1Thi,
    const float* __restrict__ b1, __bf16* __restrict__ ysq)
{
    __shared__ alignas(16) __bf16 xph[72][64];
    const int tid = threadIdx.x;
    const int bid = blockIdx.x;
    const int ocb = bid & 3;
    const int lb  = (bid >> 2) & 15;
    const int b   = bid >> 6;
    const int l0  = lb * 64;

    {
        const int row0 = tid >> 3, seg = tid & 7;
#pragma unroll
        for (int p = 0; p < 3; ++p) {
            int row = p * 32 + row0;
            if (row < 72) {
                int l = l0 - 4 + row;
                int sw = seg ^ (row & 7);
                uint4 vh = {0u,0u,0u,0u};
                if (l >= 0 && l < NL) {
                    size_t off = ((size_t)b * NL + l) * 64 + seg * 8;
                    vh = *(const uint4*)(xThi + off);
                }
                *(uint4*)(&xph[row][sw * 8]) = vh;
            }
        }
    }
    __syncthreads();

    const int lane = tid & 63, wv = tid >> 6;
    const int qq = lane >> 4, cr = lane & 15;
    const int oco = ocb * 64 + wv * 16;

    f32x4 acc[4];
#pragma unroll
    for (int lt = 0; lt < 4; ++lt) acc[lt] = (f32x4){0.f, 0.f, 0.f, 0.f};

    for (int g = 0; g < NG2; ++g) {
#pragma unroll
        for (int s = 0; s < 2; ++s) {
            size_t aoff = ((size_t)(g * NOC + oco + cr)) * 64 + s * 32 + qq * 8;
            bfv8 Ahi = *(const bfv8*)(w1Thi + aoff);
#pragma unroll
            for (int lt = 0; lt < 4; ++lt) {
                int row = lt * 16 + cr + g;
                int gr = (s * 4 + qq) ^ (row & 7);
                bfv8 Bhi = *(const bfv8*)(&xph[row][gr * 8]);
                acc[lt] = __builtin_amdgcn_mfma_f32_16x16x32_bf16(Ahi, Bhi, acc[lt], 0, 0, 0);
            }
        }
    }

    const float4 bv = *(const float4*)(b1 + oco + qq * 4);
#pragma unroll
    for (int lt = 0; lt < 4; ++lt) {
        float v0 = acc[lt][0] + bv.x, v1 = acc[lt][1] + bv.y;
        float v2 = acc[lt][2] + bv.z, v3 = acc[lt][3] + bv.w;
        float s = v0*v0 + v1*v1 + v2*v2 + v3*v3;
        float s8 = s + __shfl_xor(s, 16);
        float scale = s8 * frcp(1.0f + s8) * frsq(s8 + EPSQ);
        uint2 st;
        st.x = bfpack2(v0 * scale, v1 * scale);
        st.y = bfpack2(v2 * scale, v3 * scale);
        int l = l0 + lt * 16 + cr;
        *(uint2*)(ysq + ((size_t)b * NL + l) * NOC + oco + qq * 4) = st;
    }
}

// ---------------- k2: conv2 via MFMA + routing (R12/R13 proven version) ------
__global__ __launch_bounds__(256, 4) void k2_conv2_routing(
    const __bf16* __restrict__ ysq,
    const __bf16* __restrict__ w2hi,
    const float* __restrict__ b2, float* __restrict__ out)
{
    __shared__ alignas(16) unsigned int VbW[NCP * VROW];  // 16512 B
    __shared__ alignas(16) float cct[NCSA][36];           //  2304 B (transposed c)
    __shared__ alignas(16) float vvs[NCSA][20];           //  1280 B

    const int tid = threadIdx.x;
    const int bid = blockIdx.x;
    const int b = bid >> 10;
    const int l = bid & (NL - 1);

    const int lane = tid & 63;
    const int wv   = tid >> 6;
    const int q    = lane >> 4;
    const int cr   = lane & 15;

    const __bf16* ybase = ysq + ((size_t)b * NL + l) * NOC;
    const bool rowok = (q == 1) || (q == 0 && l > 0) || (q == 2 && l < NL - 1);
    bfv8 B0, B1;
    if (rowok) {
        B0 = *(const bfv8*)(ybase + (q - 1) * NOC + cr * 8);
        B1 = *(const bfv8*)(ybase + (q - 1) * NOC + (cr + 16) * 8);
    } else {
#pragma unroll
        for (int i = 0; i < 8; ++i) { B0[i] = (__bf16)0.0f; B1[i] = (__bf16)0.0f; }
    }

    const int swz0 = (cr & 3) << 3;
#pragma unroll
    for (int i = 0; i < 4; ++i) {
        const int t  = wv * 4 + i;
        const int oc = t * 16 + cr;
        bfv8 Ahi;
        if (q < 3) {
            Ahi = *(const bfv8*)(w2hi + oc * 24 + q * 8);
        } else {
#pragma unroll
            for (int j = 0; j < 8; ++j) Ahi[j] = (__bf16)0.0f;
        }

        f32x4 acc0 = {0.f, 0.f, 0.f, 0.f};
        f32x4 acc1 = {0.f, 0.f, 0.f, 0.f};
        acc0 = __builtin_amdgcn_mfma_f32_16x16x32_bf16(Ahi, B0, acc0, 0, 0, 0);
        acc1 = __builtin_amdgcn_mfma_f32_16x16x32_bf16(Ahi, B1, acc1, 0, 0, 0);

        // C/D layout: col(cp) = lane&15, row(oc) = q*4 + reg (+ t*16)
        const int r0 = t * 16 + q * 4;
        float4 bvv = *(const float4*)(b2 + r0);
        const int D = t * 8 + q * 2;
        const int d0 = D ^ swz0;
        VbW[cr * VROW + d0]            = bfpack2(acc0[0] + bvv.x, acc0[1] + bvv.y);
        VbW[cr * VROW + d0 + 1]        = bfpack2(acc0[2] + bvv.z, acc0[3] + bvv.w);
        VbW[(cr + 16) * VROW + d0]     = bfpack2(acc1[0] + bvv.x, acc1[1] + bvv.y);
        VbW[(cr + 16) * VROW + d0 + 1] = bfpack2(acc1[2] + bvv.z, acc1[3] + bvv.w);
    }
    __syncthreads();   // (1) V visible

    // ---- routing ----
    const int csa = tid >> 4, asa = tid & 15;   // s-step mapping (tid == oc)
    const int cp8 = tid >> 3, cs = tid & 7;     // unified softmax + a-step mapping

    const __bf16* vbB = (const __bf16*)VbW;
    float Vreg[NCP];
    {
        const int tw = tid >> 1, th = tid & 1;
#pragma unroll
        for (int cp = 0; cp < NCP; ++cp) {
            int d = tw ^ ((cp & 3) << 3);
            Vreg[cp] = (float)vbB[cp * (2 * VROW) + d * 2 + th];
        }
    }

    // a-step V rows hoisted to registers (read once, used in r0 and r1)
    unsigned int ar0[8], ar1[8];
    {
        const unsigned int* arow0 = VbW + cp8 * VROW + ((cs * 8) ^ ((cp8 & 3) << 3));
        const unsigned int* arow1 = VbW + cp8 * VROW + (((cs + 8) * 8) ^ ((cp8 & 3) << 3));
#pragma unroll
        for (int j = 0; j < 8; ++j) { ar0[j] = arow0[j]; ar1[j] = arow1[j]; }
    }

    float br0, br1;

    // ---- r = 0: logits 0 -> uniform softmax (1/16)
    {
        float s0 = 0.f, s1 = 0.f, s2 = 0.f, s3 = 0.f;
#pragma unroll
        for (int cp = 0; cp < NCP; cp += 4) {
            s0 += Vreg[cp];     s1 += Vreg[cp + 1];
            s2 += Vreg[cp + 2]; s3 += Vreg[cp + 3];
        }
        float sv = ((s0 + s1) + (s2 + s3)) * 0.0625f;
        float sq = sv * sv;
        sq += __shfl_xor(sq, 1);
        sq += __shfl_xor(sq, 2);
        sq += __shfl_xor(sq, 4);
        sq += __shfl_xor(sq, 8);
        float vval = sv * sq * frcp(1.0f + sq) * frsq(sq + EPSQ);
        vvs[csa][asa] = vval;
        __syncthreads();   // (2) vv r0

        float4 va[4], vb[4];
#pragma unroll
        for (int p = 0; p < 4; ++p) {
            va[p] = ((const float4*)(&vvs[cs][0]))[p];
            vb[p] = ((const float4*)(&vvs[cs + 8][0]))[p];
        }
        float a0a = 0.f, a0b = 0.f, a1a = 0.f, a1b = 0.f;
#pragma unroll
        for (int j = 0; j < 8; ++j) {
            unsigned int d0 = ar0[j], d1 = ar1[j];
            float ve0 = (j & 1) ? va[j >> 1].z : va[j >> 1].x;
            float vo0 = (j & 1) ? va[j >> 1].w : va[j >> 1].y;
            float ve1 = (j & 1) ? vb[j >> 1].z : vb[j >> 1].x;
            float vo1 = (j & 1) ? vb[j >> 1].w : vb[j >> 1].y;
            a0a = fmaf(__builtin_bit_cast(float, d0 << 16),          ve0, a0a);
            a0b = fmaf(__builtin_bit_cast(float, d0 & 0xFFFF0000u),  vo0, a0b);
            a1a = fmaf(__builtin_bit_cast(float, d1 << 16),          ve1, a1a);
            a1b = fmaf(__builtin_bit_cast(float, d1 & 0xFFFF0000u),  vo1, a1b);
        }
        br0 = a0a + a0b;
        br1 = a1a + a1b;
    }

    // ---- r = 1
    {
        float e0 = __expf(br0), e1 = __expf(br1);
        float ssum = e0 + e1;
        ssum += __shfl_xor(ssum, 1);
        ssum += __shfl_xor(ssum, 2);
        ssum += __shfl_xor(ssum, 4);
        float inv = frcp(ssum);
        cct[cs][cp8]     = e0 * inv;
        cct[cs + 8][cp8] = e1 * inv;
        __syncthreads();   // (3) cc r1

        float s0 = 0.f, s1 = 0.f, s2 = 0.f, s3 = 0.f;
        const float4* ccrow = (const float4*)(&cct[csa][0]);
#pragma unroll
        for (int jj = 0; jj < 8; ++jj) {
            float4 c4 = ccrow[jj];
            s0 = fmaf(c4.x, Vreg[4 * jj + 0], s0);
            s1 = fmaf(c4.y, Vreg[4 * jj + 1], s1);
            s2 = fmaf(c4.z, Vreg[4 * jj + 2], s2);
            s3 = fmaf(c4.w, Vreg[4 * jj + 3], s3);
        }
        float sv = (s0 + s1) + (s2 + s3);
        float sq = sv * sv;
        sq += __shfl_xor(sq, 1);
        sq += __shfl_xor(sq, 2);
        sq += __shfl_xor(sq, 4);
        sq += __shfl_xor(sq, 8);
        float vval = sv * sq * frcp(1.0f + sq) * frsq(sq + EPSQ);
        vvs[csa][asa] = vval;
        __syncthreads();   // (4) vv r1

        float4 va[4], vb[4];
#pragma unroll
        for (int p = 0; p < 4; ++p) {
            va[p] = ((const float4*)(&vvs[cs][0]))[p];
            vb[p] = ((const float4*)(&vvs[cs + 8][0]))[p];
        }
        float a0a = 0.f, a0b = 0.f, a1a = 0.f, a1b = 0.f;
#pragma unroll
        for (int j = 0; j < 8; ++j) {
            unsigned int d0 = ar0[j], d1 = ar1[j];
            float ve0 = (j & 1) ? va[j >> 1].z : va[j >> 1].x;
            float vo0 = (j & 1) ? va[j >> 1].w : va[j >> 1].y;
            float ve1 = (j & 1) ? vb[j >> 1].z : vb[j >> 1].x;
            float vo1 = (j & 1) ? vb[j >> 1].w : vb[j >> 1].y;
            a0a = fmaf(__builtin_bit_cast(float, d0 << 16),          ve0, a0a);
            a0b = fmaf(__builtin_bit_cast(float, d0 & 0xFFFF0000u),  vo0, a0b);
            a1a = fmaf(__builtin_bit_cast(float, d1 << 16),          ve1, a1a);
            a1b = fmaf(__builtin_bit_cast(float, d1 & 0xFFFF0000u),  vo1, a1b);
        }
        br0 += a0a + a0b;
        br1 += a1a + a1b;
    }

    // ---- r = 2 (final)
    {
        float e0 = __expf(br0), e1 = __expf(br1);
        float ssum = e0 + e1;
        ssum += __shfl_xor(ssum, 1);
        ssum += __shfl_xor(ssum, 2);
        ssum += __shfl_xor(ssum, 4);
        float inv = frcp(ssum);
        cct[cs][cp8]     = e0 * inv;
        cct[cs + 8][cp8] = e1 * inv;
        __syncthreads();   // (5) cc r2

        float s0 = 0.f, s1 = 0.f, s2 = 0.f, s3 = 0.f;
        const float4* ccrow = (const float4*)(&cct[csa][0]);
#pragma unroll
        for (int jj = 0; jj < 8; ++jj) {
            float4 c4 = ccrow[jj];
            s0 = fmaf(c4.x, Vreg[4 * jj + 0], s0);
            s1 = fmaf(c4.y, Vreg[4 * jj + 1], s1);
            s2 = fmaf(c4.z, Vreg[4 * jj + 2], s2);
            s3 = fmaf(c4.w, Vreg[4 * jj + 3], s3);
        }
        float sv = (s0 + s1) + (s2 + s3);
        float sq = sv * sv;
        sq += __shfl_xor(sq, 1);
        sq += __shfl_xor(sq, 2);
        sq += __shfl_xor(sq, 4);
        sq += __shfl_xor(sq, 8);
        float vval = sv * sq * frcp(1.0f + sq) * frsq(sq + EPSQ);
        out[((size_t)b * NL + l) * NOC + tid] = vval;
    }
}

extern "C" void kernel_launch(void* const* d_in, const int* in_sizes, int n_in,
                              void* d_out, int out_size, void* d_ws, size_t ws_size,
                              hipStream_t stream)
{
    const float* x  = (const float*)d_in[0];
    const float* w1 = (const float*)d_in[1];
    const float* b1 = (const float*)d_in[2];
    const float* w2 = (const float*)d_in[3];
    const float* b2 = (const float*)d_in[4];
    float* outp = (float*)d_out;

    char* ws = (char*)d_ws;
    __bf16* ysq   = (__bf16*)(ws);                 // 4,194,304
    __bf16* xThi  = (__bf16*)(ws + 4194304);       // 1,048,576
    __bf16* w1Thi = (__bf16*)(ws + 5242880);       //   294,912
    __bf16* w2hi  = (__bf16*)(ws + 5537792);       //    12,288

    k0_prep<<<417, 256, 0, stream>>>(x, w1, w2, xThi, w1Thi, w2hi);
    k1_mfma<<<512, 256, 0, stream>>>(xThi, w1Thi, b1, ysq);
    k2_conv2_routing<<<NB * NL, 256, 0, stream>>>(ysq, w2hi, b2, outp);
}